// Round 12
// baseline (571.486 us; speedup 1.0000x reference)
//
#include <hip/hip_runtime.h>
#include <math.h>

#define NN 8192
#define NE 65536
#define NB 512
#define SQRT3F 1.7320508075688772f
#define INV_SQRT3F 0.5773502691896258f
#define PW 0.17677669529663687f      // 1/sqrt(32) == 0.25/sqrt(2)
#define GSTEP (10.0f/31.0f)
#define GCOEFF (-0.5f/(GSTEP*GSTEP))

typedef _Float16 f16;
typedef f16 f16x2 __attribute__((ext_vector_type(2)));
typedef f16 f16x4 __attribute__((ext_vector_type(4)));
typedef f16 f16x8 __attribute__((ext_vector_type(8)));
typedef float f32x4 __attribute__((ext_vector_type(4)));

#define MFMA(acc, a, b) acc = __builtin_amdgcn_mfma_f32_16x16x32_f16(a, b, acc, 0, 0, 0)

struct KP {
    const float *c0w1, *c0b1, *c1w1, *c1b1, *c0w2, *c0b2, *c1w2, *c1b2;
    f16 *w1c0, *w1c1, *w2t0, *w2t1;
    const float *xr, *xp;
    float* h16f; f16* h16_16;
    const float *nw1, *nb1, *nw2, *nb2;
    const int *eir, *eip;
    const float *posr, *posp;
    float* sh1d; f16* eemb16; int* cnt;
    const float *ew1, *eb1, *ew2, *eb2;
    int* rowptr; int* eord;
    f16* tp0; f16* tp1;
    float* h64f; f16* h64_16;
    float* xf;
    const int *batchr, *batchp;
    const float *snw1, *snb1, *snw2, *snb2, *snw3, *snb3;
    const float *sew1, *seb1, *sew2, *seb2, *sew3, *seb3;
    float* out;
    int* bar;
};

// Manual grid barrier: monotonic counter, release/acquire agent fences.
// Co-residency guaranteed: 55296B LDS -> 2 blocks/CU x 256 CU = 512 = grid.
// Bounded spin (fails loudly instead of hanging if assumption breaks).
__device__ __forceinline__ void gridbar(int* bar, int phase) {
    __syncthreads();
    if (threadIdx.x == 0) {
        __threadfence();                       // release: flush this block's writes
        atomicAdd(bar, 1);
        int target = (phase + 1) * NB;
        int it = 0;
        while (atomicAdd(bar, 0) < target && it < (1 << 22)) {
            ++it;
            __builtin_amdgcn_s_sleep(8);
        }
    }
    __syncthreads();
    __threadfence();                           // acquire: invalidate stale caches
}

__global__ __launch_bounds__(128) void k_mega(KP P) {
    __shared__ __align__(16) char smem[55296];   // max phase: conv1 (36864 ea + 18432 sc1)
    int bid = blockIdx.x, tid = threadIdx.x;
    int gtid = bid * 128 + tid;

    // ================= P1: weight prep | node MLP | edge geom | out zero =================
    if (gtid < 64) P.out[gtid] = 0.f;
    {   // weight prep: 81920 items, 2 per thread
#pragma unroll
        for (int it = 0; it < 2; ++it) {
            int idx = gtid + it * 65536;
            if (idx < 1280 * 64) {
                int n = idx >> 6, h = idx & 63;
                P.w2t1[idx] = (f16)((h < 48) ? P.c1w2[h * 1280 + n] : (h == 48 ? P.c1b2[n] : 0.f));
                if (n < 512) P.w2t0[idx] = (f16)((h < 48) ? P.c0w2[h * 512 + n] : (h == 48 ? P.c0b2[n] : 0.f));
                if (n < 48) {
                    P.w1c0[idx] = (f16)((h < 48) ? P.c0w1[h * 48 + n] : (h == 48 ? P.c0b1[n] : 0.f));
                    P.w1c1[idx] = (f16)((h < 48) ? P.c1w1[h * 48 + n] : (h == 48 ? P.c1b1[n] : 0.f));
                }
            }
        }
    }
    if (gtid < 2 * NN) {   // node MLP x(32)->16->16
        int mol = gtid >> 13;
        int v = gtid & (NN - 1);
        const float* x = mol ? P.xp : P.xr;
        float* hf = P.h16f + (size_t)mol * NN * 16;
        f16* h16o = P.h16_16 + (size_t)mol * NN * 16;
        float xi[32];
#pragma unroll
        for (int i = 0; i < 32; i++) xi[i] = x[v * 32 + i];
        float a[16];
#pragma unroll
        for (int j = 0; j < 16; j++) a[j] = P.nb1[j];
#pragma unroll
        for (int i = 0; i < 32; i++)
#pragma unroll
            for (int j = 0; j < 16; j++) a[j] = fmaf(xi[i], P.nw1[i * 16 + j], a[j]);
#pragma unroll
        for (int j = 0; j < 16; j++) a[j] = fmaxf(a[j], 0.f);
        float o[16];
#pragma unroll
        for (int j = 0; j < 16; j++) o[j] = P.nb2[j];
#pragma unroll
        for (int i = 0; i < 16; i++)
#pragma unroll
            for (int j = 0; j < 16; j++) o[j] = fmaf(a[i], P.nw2[i * 16 + j], o[j]);
#pragma unroll
        for (int j = 0; j < 16; j++) { hf[v * 16 + j] = o[j]; h16o[v * 16 + j] = (f16)o[j]; }
    }
    {   // edge geom + RBF + edge MLP + dst histogram, both mols
#pragma unroll 1
        for (int mol = 0; mol < 2; ++mol) {
            const int* ei = mol ? P.eip : P.eir;
            const float* pos = mol ? P.posp : P.posr;
            float* sh_ = P.sh1d + (size_t)mol * NE * 4;
            f16* em_ = P.eemb16 + (size_t)mol * NE * 16;
            int* cn_ = P.cnt + mol * NN;
            int e = gtid;
            int s = ei[e], d = ei[NE + e];
            float ex = pos[d * 3 + 0] - pos[s * 3 + 0];
            float ey = pos[d * 3 + 1] - pos[s * 3 + 1];
            float ez = pos[d * 3 + 2] - pos[s * 3 + 2];
            float dist = sqrtf(ex * ex + ey * ey + ez * ez + 1e-12f);
            float inv = SQRT3F / dist;
            sh_[e * 4 + 0] = ex * inv;
            sh_[e * 4 + 1] = ey * inv;
            sh_[e * 4 + 2] = ez * inv;
            sh_[e * 4 + 3] = dist;
            float g[32];
#pragma unroll
            for (int i = 0; i < 32; i++) {
                float t = dist - (float)i * GSTEP;
                g[i] = __expf(GCOEFF * t * t);
            }
            float a[16];
#pragma unroll
            for (int j = 0; j < 16; j++) a[j] = P.eb1[j];
#pragma unroll
            for (int i = 0; i < 32; i++)
#pragma unroll
                for (int j = 0; j < 16; j++) a[j] = fmaf(g[i], P.ew1[i * 16 + j], a[j]);
#pragma unroll
            for (int j = 0; j < 16; j++) a[j] = fmaxf(a[j], 0.f);
            float o[16];
#pragma unroll
            for (int j = 0; j < 16; j++) o[j] = P.eb2[j];
#pragma unroll
            for (int i = 0; i < 16; i++)
#pragma unroll
                for (int j = 0; j < 16; j++) o[j] = fmaf(a[i], P.ew2[i * 16 + j], o[j]);
#pragma unroll
            for (int j = 0; j < 16; j++) em_[e * 16 + j] = (f16)o[j];
            atomicAdd(&cn_[d], 1);
        }
    }
    gridbar(P.bar, 0);

    // ================= P2: CSR scan (blocks 0,1); zeroes cnt for reuse =================
    if (bid < 2) {
        int* part = (int*)smem;
        int mol = bid;
        int* c = P.cnt + mol * NN;
        int* rp = P.rowptr + mol * (NN + 1);
        int base = tid * (NN / 128);
        int s = 0;
#pragma unroll
        for (int i = 0; i < NN / 128; i++) s += c[base + i];
        part[tid] = s;
        __syncthreads();
        if (tid == 0) {
            int run = 0;
            for (int i = 0; i < 128; i++) { int v = part[i]; part[i] = run; run += v; }
        }
        __syncthreads();
        int run = part[tid];
        for (int i = 0; i < NN / 128; i++) {
            int cv = c[base + i];
            rp[base + i] = run;
            run += cv;
            c[base + i] = 0;
        }
        if (tid == 127) rp[NN] = run;
    }
    gridbar(P.bar, 1);

    // ================= P3: CSR fill, both mols =================
#pragma unroll 1
    for (int mol = 0; mol < 2; ++mol) {
        const int* ei = mol ? P.eip : P.eir;
        int e = gtid;
        int d = ei[NE + e];
        int pos = atomicAdd(&P.cnt[mol * NN + d], 1);
        P.eord[mol * NE + P.rowptr[mol * (NN + 1) + d] + pos] = e;
    }
    gridbar(P.bar, 2);

    // ================= P4: conv0 (256 edges/block, 128/wave) =================
    {
        f16* ea = (f16*)smem;                       // 256*72
        f16* sc0 = (f16*)(smem + 36864);            // 256*24
        float4* shs = (float4*)(smem + 49152);      // 256
        int mol = bid >> 8;
        int cb = bid & 255;
        const int* ei = mol ? P.eip : P.eir;
        const int* eo = P.eord + mol * NE;
        const f16* em_ = P.eemb16 + (size_t)mol * NE * 16;
        const f16* h16_ = P.h16_16 + (size_t)mol * NN * 16;
        const float* sh_ = P.sh1d + (size_t)mol * NE * 4;
        f16* tp_ = P.tp0 + (size_t)mol * NE * 64;
        int e0 = cb * 256;
#pragma unroll
        for (int ii = 0; ii < 2; ii++) {
            int er = tid * 2 + ii;
            int le = eo[e0 + er];
            int s = ei[le], d = ei[NE + le];
            char* row = smem + er * 144;
            const f16x8* pe = (const f16x8*)(em_ + (size_t)le * 16);
            ((f16x8*)row)[0] = pe[0]; ((f16x8*)row)[1] = pe[1];
            const f16x8* pd = (const f16x8*)(h16_ + (size_t)d * 16);
            ((f16x8*)row)[2] = pd[0]; ((f16x8*)row)[3] = pd[1];
            const f16x8* ps = (const f16x8*)(h16_ + (size_t)s * 16);
            f16x8 sv0 = ps[0], sv1 = ps[1];
            ((f16x8*)row)[4] = sv0; ((f16x8*)row)[5] = sv1;
            f16x8 z = {}; f16x8 o = {}; o[0] = (f16)1.0f;
            ((f16x8*)row)[6] = o; ((f16x8*)row)[7] = z; ((f16x8*)row)[8] = z;
            char* srow = (char*)sc0 + er * 48;
            *(f16x8*)srow = sv0;
            *(f16x8*)(srow + 16) = sv1;
            shs[er] = *(const float4*)(sh_ + (size_t)le * 4);
        }
        __syncthreads();
        int wv = tid >> 6, l = tid & 63;
        int koff = (l >> 4) * 16;
        int voffB = (l & 15) * 128 + koff;
        int rbase = wv * 128;
#pragma unroll
        for (int t = 0; t < 8; t++) {
            int arow = rbase + t * 16 + (l & 15);
            f16x8 a0 = *(const f16x8*)((const char*)ea + arow * 144 + koff);
            f16x8 a1 = *(const f16x8*)((const char*)ea + arow * 144 + koff + 64);
#pragma unroll
            for (int nt = 0; nt < 3; nt++) {
                f32x4 hacc = {0.f, 0.f, 0.f, 0.f};
                const char* hb = (const char*)P.w1c0 + nt * 2048 + voffB;
                MFMA(hacc, a0, *(const f16x8*)(hb));
                MFMA(hacc, a1, *(const f16x8*)(hb + 64));
#pragma unroll
                for (int r = 0; r < 4; r++) {
                    int rr = rbase + t * 16 + (l >> 4) * 4 + r;
                    ea[rr * 72 + nt * 16 + (l & 15)] = (f16)fmaxf(hacc[r], 0.f);
                }
            }
        }
        f16x8 ha0[8], ha1[8];
#pragma unroll
        for (int t = 0; t < 8; t++) {
            int arow = rbase + t * 16 + (l & 15);
            ha0[t] = *(const f16x8*)((const char*)ea + arow * 144 + koff);
            ha1[t] = *(const f16x8*)((const char*)ea + arow * 144 + koff + 64);
        }
        f32x4 accA[8] = {}, accB[8] = {};
        const char* wB = (const char*)P.w2t0 + voffB;
        f16x8 cA0 = *(const f16x8*)(wB), cA1 = *(const f16x8*)(wB + 64);
        f16x8 cB0 = *(const f16x8*)(wB + 32768), cB1 = *(const f16x8*)(wB + 32768 + 64);
#pragma unroll 4
        for (int u = 0; u < 16; ++u) {
            int un = (u < 15) ? u + 1 : 15;
            const char* Hb = wB + un * 2048;
            f16x8 nA0 = *(const f16x8*)(Hb), nA1 = *(const f16x8*)(Hb + 64);
            f16x8 nB0 = *(const f16x8*)(Hb + 32768), nB1 = *(const f16x8*)(Hb + 32768 + 64);
#pragma unroll
            for (int t = 0; t < 8; t++) {
                f16 s = *(const f16*)((const char*)sc0 + (rbase + t * 16 + (l & 15)) * 48 + u * 2);
                f16x8 x0 = ha0[t] * s, x1 = ha1[t] * s;
                MFMA(accA[t], x0, cA0); MFMA(accA[t], x1, cA1);
                MFMA(accB[t], x0, cB0); MFMA(accB[t], x1, cB1);
            }
            cA0 = nA0; cA1 = nA1; cB0 = nB0; cB1 = nB1;
        }
        int w = l & 15;
#pragma unroll
        for (int t = 0; t < 8; t++)
#pragma unroll
            for (int r = 0; r < 4; r++) {
                int ro = rbase + t * 16 + (l >> 4) * 4 + r;
                int i = e0 + ro;
                float4 shv = shs[ro];
                f16* tpp = tp_ + (size_t)i * 64;
                float tb = 0.25f * accB[t][r];
                tpp[w] = (f16)(0.25f * accA[t][r]);
                tpp[16 + w] = (f16)(tb * shv.x);
                tpp[32 + w] = (f16)(tb * shv.y);
                tpp[48 + w] = (f16)(tb * shv.z);
            }
    }
    gridbar(P.bar, 3);

    // ================= P5: gather conv0 (32 nodes/block, 4 thr/node) =================
    {
        int mol = bid >> 8;
        const float* h_ = P.h16f + (size_t)mol * NN * 16;
        const f16* tp = P.tp0 + (size_t)mol * NE * 64;
        const int* rp = P.rowptr + mol * (NN + 1);
        float* o_ = P.h64f + (size_t)mol * NN * 64;
        f16* o16_ = P.h64_16 + (size_t)mol * NN * 16;
        int v = (bid & 255) * 32 + (tid >> 2), q = tid & 3;
        int r0 = rp[v], r1 = rp[v + 1];
        float acc[16];
#pragma unroll
        for (int j = 0; j < 16; j++) acc[j] = 0.f;
        for (int i = r0; i < r1; i++) {
            const f16* src = tp + (size_t)i * 64 + q * 16;
            f16x8 v0 = *(const f16x8*)src;
            f16x8 v1 = *(const f16x8*)(src + 8);
#pragma unroll
            for (int j = 0; j < 8; j++) { acc[j] += (float)v0[j]; acc[8 + j] += (float)v1[j]; }
        }
        float rc = 1.0f / fmaxf((float)(r1 - r0), 1.0f);
        if (q == 0) {
#pragma unroll
            for (int w = 0; w < 16; w++) {
                float val = fmaf(acc[w], rc, h_[(size_t)v * 16 + w]);
                o_[(size_t)v * 64 + w] = val;
                o16_[(size_t)v * 16 + w] = (f16)val;
            }
        } else {
#pragma unroll
            for (int w = 0; w < 16; w++) o_[(size_t)v * 64 + 16 + 3 * w + (q - 1)] = acc[w] * rc;
        }
    }
    gridbar(P.bar, 4);

    // ================= P6: conv1 (mats A+D) =================
    {
        f16* ea = (f16*)smem;                    // 256*72
        f16* sc1 = (f16*)(smem + 36864);         // 256*36
        int mol = bid >> 8;
        int cb = bid & 255;
        const int* ei = mol ? P.eip : P.eir;
        const int* eo = P.eord + mol * NE;
        const f16* em_ = P.eemb16 + (size_t)mol * NE * 16;
        const f16* h16_ = P.h64_16 + (size_t)mol * NN * 16;
        const float* hf_ = P.h64f + (size_t)mol * NN * 64;
        const float* sh_ = P.sh1d + (size_t)mol * NE * 4;
        f16* tp_ = P.tp1 + (size_t)mol * NE * 16;
        int e0 = cb * 256;
#pragma unroll
        for (int ii = 0; ii < 2; ii++) {
            int er = tid * 2 + ii;
            int le = eo[e0 + er];
            int s = ei[le], d = ei[NE + le];
            char* row = smem + er * 144;
            const f16x8* pe = (const f16x8*)(em_ + (size_t)le * 16);
            ((f16x8*)row)[0] = pe[0]; ((f16x8*)row)[1] = pe[1];
            const f16x8* pd = (const f16x8*)(h16_ + (size_t)d * 16);
            ((f16x8*)row)[2] = pd[0]; ((f16x8*)row)[3] = pd[1];
            const f16x8* ps = (const f16x8*)(h16_ + (size_t)s * 16);
            ((f16x8*)row)[4] = ps[0]; ((f16x8*)row)[5] = ps[1];
            f16x8 z = {}; f16x8 o = {}; o[0] = (f16)1.0f;
            ((f16x8*)row)[6] = o; ((f16x8*)row)[7] = z; ((f16x8*)row)[8] = z;
            float4 shv = *(const float4*)(sh_ + (size_t)le * 4);
            const float* hfs = hf_ + (size_t)s * 64;
            float xu[16];
#pragma unroll
            for (int g = 0; g < 4; g++) {
                float4 v4 = *(const float4*)(hfs + g * 4);
                xu[g * 4 + 0] = v4.x; xu[g * 4 + 1] = v4.y; xu[g * 4 + 2] = v4.z; xu[g * 4 + 3] = v4.w;
            }
            float x1v[48];
#pragma unroll
            for (int g = 0; g < 12; g++) {
                float4 v4 = *(const float4*)(hfs + 16 + g * 4);
                x1v[g * 4 + 0] = v4.x; x1v[g * 4 + 1] = v4.y; x1v[g * 4 + 2] = v4.z; x1v[g * 4 + 3] = v4.w;
            }
            char* srow = (char*)sc1 + er * 72;
#pragma unroll
            for (int g = 0; g < 4; g++) {
                f16x8 pk;
#pragma unroll
                for (int k2 = 0; k2 < 4; k2++) {
                    int k = g * 4 + k2;
                    float du = (x1v[k * 3] * shv.x + x1v[k * 3 + 1] * shv.y + x1v[k * 3 + 2] * shv.z) * INV_SQRT3F;
                    pk[k2 * 2 + 0] = (f16)xu[k];
                    pk[k2 * 2 + 1] = (f16)du;
                }
                *(f16x8*)(srow + g * 16) = pk;
            }
        }
        __syncthreads();
        int wv = tid >> 6, l = tid & 63;
        int koff = (l >> 4) * 16;
        int voffB = (l & 15) * 128 + koff;
        int rbase = wv * 128;
#pragma unroll
        for (int t = 0; t < 8; t++) {
            int arow = rbase + t * 16 + (l & 15);
            f16x8 a0 = *(const f16x8*)((const char*)ea + arow * 144 + koff);
            f16x8 a1 = *(const f16x8*)((const char*)ea + arow * 144 + koff + 64);
#pragma unroll
            for (int nt = 0; nt < 3; nt++) {
                f32x4 hacc = {0.f, 0.f, 0.f, 0.f};
                const char* hb = (const char*)P.w1c1 + nt * 2048 + voffB;
                MFMA(hacc, a0, *(const f16x8*)(hb));
                MFMA(hacc, a1, *(const f16x8*)(hb + 64));
#pragma unroll
                for (int r = 0; r < 4; r++) {
                    int rr = rbase + t * 16 + (l >> 4) * 4 + r;
                    ea[rr * 72 + nt * 16 + (l & 15)] = (f16)fmaxf(hacc[r], 0.f);
                }
            }
        }
        f16x8 ha0[8], ha1[8];
#pragma unroll
        for (int t = 0; t < 8; t++) {
            int arow = rbase + t * 16 + (l & 15);
            ha0[t] = *(const f16x8*)((const char*)ea + arow * 144 + koff);
            ha1[t] = *(const f16x8*)((const char*)ea + arow * 144 + koff + 64);
        }
        f32x4 accA[8] = {};
        const char* wB = (const char*)P.w2t1 + voffB;
        f16x8 cA0 = *(const f16x8*)(wB), cA1 = *(const f16x8*)(wB + 64);
        f16x8 cD0 = *(const f16x8*)(wB + 98304), cD1 = *(const f16x8*)(wB + 98304 + 64);
#pragma unroll 4
        for (int u = 0; u < 16; ++u) {
            int un = (u < 15) ? u + 1 : 15;
            const char* Hb = wB + un * 2048;
            f16x8 nA0 = *(const f16x8*)(Hb), nA1 = *(const f16x8*)(Hb + 64);
            f16x8 nD0 = *(const f16x8*)(Hb + 98304), nD1 = *(const f16x8*)(Hb + 98304 + 64);
#pragma unroll
            for (int t = 0; t < 8; t++) {
                f16x2 sp = *(const f16x2*)((const char*)sc1 + (rbase + t * 16 + (l & 15)) * 72 + u * 4);
                f16x8 x0 = ha0[t] * sp[0], x1 = ha1[t] * sp[0];
                MFMA(accA[t], x0, cA0); MFMA(accA[t], x1, cA1);
                x0 = ha0[t] * sp[1]; x1 = ha1[t] * sp[1];
                MFMA(accA[t], x0, cD0); MFMA(accA[t], x1, cD1);
            }
            cA0 = nA0; cA1 = nA1; cD0 = nD0; cD1 = nD1;
        }
        int w = l & 15;
#pragma unroll
        for (int t = 0; t < 8; t++)
#pragma unroll
            for (int r = 0; r < 4; r++) {
                int i = e0 + rbase + t * 16 + (l >> 4) * 4 + r;
                tp_[(size_t)i * 16 + w] = (f16)(PW * accA[t][r]);
            }
    }
    gridbar(P.bar, 5);

    // ================= P7: gather conv1 -> xf; s_nodes MLP; bucket =================
    {
        float (*xfs)[17] = (float(*)[17])smem;        // 32*17*4
        float* buck = (float*)(smem + 2304);          // 64*4
        if (tid < 64) buck[tid] = 0.f;
        int mol = bid >> 8;
        float sign = mol ? 1.f : -1.f;
        const int* batch = mol ? P.batchp : P.batchr;
        const float* h_ = P.h64f + (size_t)mol * NN * 64;
        const f16* tp = P.tp1 + (size_t)mol * NE * 16;
        const int* rp = P.rowptr + mol * (NN + 1);
        float* xf_ = P.xf + (size_t)mol * NN * 16;
        int v = (bid & 255) * 32 + (tid >> 2), q = tid & 3;
        int r0 = rp[v], r1 = rp[v + 1];
        float a0 = 0.f, a1 = 0.f, a2 = 0.f, a3 = 0.f;
        for (int i = r0; i < r1; i++) {
            f16x4 t4 = *(const f16x4*)(tp + (size_t)i * 16 + q * 4);
            a0 += (float)t4[0]; a1 += (float)t4[1]; a2 += (float)t4[2]; a3 += (float)t4[3];
        }
        float rc = 1.0f / fmaxf((float)(r1 - r0), 1.0f);
        float4 hv = *(const float4*)(h_ + (size_t)v * 64 + q * 4);
        float4 xv4;
        xv4.x = fmaf(a0, rc, hv.x); xv4.y = fmaf(a1, rc, hv.y);
        xv4.z = fmaf(a2, rc, hv.z); xv4.w = fmaf(a3, rc, hv.w);
        xfs[tid >> 2][q * 4 + 0] = xv4.x; xfs[tid >> 2][q * 4 + 1] = xv4.y;
        xfs[tid >> 2][q * 4 + 2] = xv4.z; xfs[tid >> 2][q * 4 + 3] = xv4.w;
        *(float4*)(xf_ + (size_t)v * 16 + q * 4) = xv4;
        __syncthreads();
        if (tid < 32) {
            int v2 = (bid & 255) * 32 + tid;
            float xv[16];
#pragma unroll
            for (int c = 0; c < 16; c++) xv[c] = xfs[tid][c];
            float aa[32];
#pragma unroll
            for (int j = 0; j < 32; j++) aa[j] = P.snb1[j];
#pragma unroll
            for (int i = 0; i < 16; i++)
#pragma unroll
                for (int j = 0; j < 32; j++) aa[j] = fmaf(xv[i], P.snw1[i * 32 + j], aa[j]);
#pragma unroll
            for (int j = 0; j < 32; j++) aa[j] = fmaxf(aa[j], 0.f);
            float bb[16];
#pragma unroll
            for (int j = 0; j < 16; j++) bb[j] = P.snb2[j];
#pragma unroll
            for (int i = 0; i < 32; i++)
#pragma unroll
                for (int j = 0; j < 16; j++) bb[j] = fmaf(aa[i], P.snw2[i * 16 + j], bb[j]);
#pragma unroll
            for (int j = 0; j < 16; j++) bb[j] = fmaxf(bb[j], 0.f);
            float val = P.snb3[0];
#pragma unroll
            for (int i = 0; i < 16; i++) val = fmaf(bb[i], P.snw3[i], val);
            atomicAdd(&buck[batch[v2]], val);
        }
        __syncthreads();
        if (tid < 64) atomicAdd(&P.out[tid], sign * buck[tid]);
    }
    gridbar(P.bar, 6);

    // ================= P8: s_edges MLP, both mols =================
    {
        float* buck = (float*)smem;
        if (tid < 64) buck[tid] = 0.f;
        __syncthreads();
#pragma unroll 1
        for (int mol = 0; mol < 2; ++mol) {
            float sign = mol ? 1.f : -1.f;
            const int* ei = mol ? P.eip : P.eir;
            const int* batch = mol ? P.batchp : P.batchr;
            const float* sh_ = P.sh1d + (size_t)mol * NE * 4;
            const float* xf_ = P.xf + (size_t)mol * NN * 16;
            int e = gtid;
            int s = ei[e], d = ei[NE + e];
            float dist = sh_[e * 4 + 3];
            float in[64];
#pragma unroll
            for (int i = 0; i < 32; i++) {
                float t = dist - (float)i * GSTEP;
                in[i] = __expf(GCOEFF * t * t);
            }
#pragma unroll
            for (int i = 0; i < 16; i++) in[32 + i] = xf_[s * 16 + i];
#pragma unroll
            for (int i = 0; i < 16; i++) in[48 + i] = xf_[d * 16 + i];
            float a[16];
#pragma unroll
            for (int j = 0; j < 16; j++) a[j] = P.seb1[j];
#pragma unroll
            for (int i = 0; i < 64; i++)
#pragma unroll
                for (int j = 0; j < 16; j++) a[j] = fmaf(in[i], P.sew1[i * 16 + j], a[j]);
#pragma unroll
            for (int j = 0; j < 16; j++) a[j] = fmaxf(a[j], 0.f);
            float bb[16];
#pragma unroll
            for (int j = 0; j < 16; j++) bb[j] = P.seb2[j];
#pragma unroll
            for (int i = 0; i < 16; i++)
#pragma unroll
                for (int j = 0; j < 16; j++) bb[j] = fmaf(a[i], P.sew2[i * 16 + j], bb[j]);
#pragma unroll
            for (int j = 0; j < 16; j++) bb[j] = fmaxf(bb[j], 0.f);
            float val = P.seb3[0];
#pragma unroll
            for (int i = 0; i < 16; i++) val = fmaf(bb[i], P.sew3[i], val);
            atomicAdd(&buck[batch[s]], sign * val);
        }
        __syncthreads();
        if (tid < 64) atomicAdd(&P.out[tid], buck[tid]);
    }
}

extern "C" void kernel_launch(void* const* d_in, const int* in_sizes, int n_in,
                              void* d_out, int out_size, void* d_ws, size_t ws_size,
                              hipStream_t stream) {
    KP kp;
    kp.xr = (const float*)d_in[0];
    kp.posr = (const float*)d_in[1];
    kp.eir = (const int*)d_in[2];
    kp.batchr = (const int*)d_in[3];
    kp.xp = (const float*)d_in[4];
    kp.posp = (const float*)d_in[5];
    kp.eip = (const int*)d_in[6];
    kp.batchp = (const int*)d_in[7];
    kp.nw1 = (const float*)d_in[8];
    kp.nb1 = (const float*)d_in[9];
    kp.nw2 = (const float*)d_in[10];
    kp.nb2 = (const float*)d_in[11];
    kp.ew1 = (const float*)d_in[12];
    kp.eb1 = (const float*)d_in[13];
    kp.ew2 = (const float*)d_in[14];
    kp.eb2 = (const float*)d_in[15];
    kp.c0w1 = (const float*)d_in[16];
    kp.c0b1 = (const float*)d_in[17];
    kp.c0w2 = (const float*)d_in[18];
    kp.c0b2 = (const float*)d_in[19];
    kp.c1w1 = (const float*)d_in[20];
    kp.c1b1 = (const float*)d_in[21];
    kp.c1w2 = (const float*)d_in[22];
    kp.c1b2 = (const float*)d_in[23];
    kp.snw1 = (const float*)d_in[24];
    kp.snb1 = (const float*)d_in[25];
    kp.snw2 = (const float*)d_in[26];
    kp.snb2 = (const float*)d_in[27];
    kp.snw3 = (const float*)d_in[28];
    kp.snb3 = (const float*)d_in[29];
    kp.sew1 = (const float*)d_in[30];
    kp.seb1 = (const float*)d_in[31];
    kp.sew2 = (const float*)d_in[32];
    kp.seb2 = (const float*)d_in[33];
    kp.sew3 = (const float*)d_in[34];
    kp.seb3 = (const float*)d_in[35];
    kp.out = (float*)d_out;

    char* p = (char*)d_ws;
    auto alloc = [&](size_t bytes) { char* r = p; p += (bytes + 255) & ~(size_t)255; return r; };
    kp.w2t1 = (f16*)alloc(1280 * 64 * 2);
    kp.w2t0 = (f16*)alloc(512 * 64 * 2);
    kp.w1c0 = (f16*)alloc(48 * 64 * 2);
    kp.w1c1 = (f16*)alloc(48 * 64 * 2);
    kp.eemb16 = (f16*)alloc((size_t)2 * NE * 16 * 2);
    kp.h16_16 = (f16*)alloc((size_t)2 * NN * 16 * 2);
    kp.h64_16 = (f16*)alloc((size_t)2 * NN * 16 * 2);
    kp.h16f = (float*)alloc((size_t)2 * NN * 16 * 4);
    kp.sh1d = (float*)alloc((size_t)2 * NE * 4 * 4);
    kp.cnt = (int*)alloc((size_t)2 * NN * 4);
    kp.bar = (int*)alloc(256);                         // barrier counter, right after cnt
    kp.rowptr = (int*)alloc((size_t)2 * (NN + 1) * 4);
    kp.eord = (int*)alloc((size_t)2 * NE * 4);
    kp.tp0 = (f16*)alloc((size_t)2 * NE * 64 * 2);
    kp.tp1 = kp.tp0;                                   // reused after P5 consumes tp0
    kp.h64f = (float*)alloc((size_t)2 * NN * 64 * 4);
    kp.xf = (float*)alloc((size_t)2 * NN * 16 * 4);
    (void)ws_size; (void)n_in; (void)in_sizes; (void)out_size;

    // zero cnt (histogram) + bar (grid barrier) in one memset
    hipMemsetAsync(kp.cnt, 0, (size_t)2 * NN * 4 + 256, stream);

    k_mega<<<dim3(NB, 1, 1), dim3(128, 1, 1), 0, stream>>>(kp);
}

// Round 13
// 142.468 us; speedup vs baseline: 4.0113x; 4.0113x over previous
//
#include <hip/hip_runtime.h>
#include <math.h>

#define NN 8192
#define NE 65536
#define SQRT3F 1.7320508075688772f
#define INV_SQRT3F 0.5773502691896258f
#define PW 0.17677669529663687f      // 1/sqrt(32) == 0.25/sqrt(2)
#define GSTEP (10.0f/31.0f)
#define GCOEFF (-0.5f/(GSTEP*GSTEP))

typedef _Float16 f16;
typedef f16 f16x2 __attribute__((ext_vector_type(2)));
typedef f16 f16x4 __attribute__((ext_vector_type(4)));
typedef f16 f16x8 __attribute__((ext_vector_type(8)));
typedef float f32x4 __attribute__((ext_vector_type(4)));

#define MFMA(acc, a, b) acc = __builtin_amdgcn_mfma_f32_16x16x32_f16(a, b, acc, 0, 0, 0)

// ============ fused pre-pass: [0,320) weight prep | [320,384) node MLP | [384,896) edge geom ============
__global__ __launch_bounds__(256) void k_pre(const float* __restrict__ c0w1, const float* __restrict__ c0b1,
                                             const float* __restrict__ c1w1, const float* __restrict__ c1b1,
                                             const float* __restrict__ c0w2, const float* __restrict__ c0b2,
                                             const float* __restrict__ c1w2, const float* __restrict__ c1b2,
                                             f16* __restrict__ w1c0, f16* __restrict__ w1c1,
                                             f16* __restrict__ w2t0, f16* __restrict__ w2t1,
                                             const float* __restrict__ xr, const float* __restrict__ xp,
                                             float* __restrict__ h16f, f16* __restrict__ h16_16,
                                             const float* __restrict__ nw1, const float* __restrict__ nb1,
                                             const float* __restrict__ nw2, const float* __restrict__ nb2,
                                             const int* __restrict__ eir, const int* __restrict__ eip,
                                             const float* __restrict__ posr, const float* __restrict__ posp,
                                             float* __restrict__ sh1d, f16* __restrict__ eemb16,
                                             int* __restrict__ cnt,
                                             const float* __restrict__ ew1, const float* __restrict__ eb1,
                                             const float* __restrict__ ew2, const float* __restrict__ eb2) {
    int b = blockIdx.x;
    int tid = threadIdx.x;
    if (b < 320) {
        int idx = b * 256 + tid;
        if (idx >= 1280 * 64) return;
        int n = idx >> 6, h = idx & 63;
        w2t1[idx] = (f16)((h < 48) ? c1w2[h * 1280 + n] : (h == 48 ? c1b2[n] : 0.f));
        if (n < 512) w2t0[idx] = (f16)((h < 48) ? c0w2[h * 512 + n] : (h == 48 ? c0b2[n] : 0.f));
        if (n < 48) {
            w1c0[idx] = (f16)((h < 48) ? c0w1[h * 48 + n] : (h == 48 ? c0b1[n] : 0.f));
            w1c1[idx] = (f16)((h < 48) ? c1w1[h * 48 + n] : (h == 48 ? c1b1[n] : 0.f));
        }
    } else if (b < 384) {
        int bb = b - 320;
        int mol = bb >> 5;
        const float* x = mol ? xp : xr;
        float* hf = h16f + (size_t)mol * NN * 16;
        f16* h16o = h16_16 + (size_t)mol * NN * 16;
        int v = (bb & 31) * 256 + tid;
        float xi[32];
#pragma unroll
        for (int i = 0; i < 32; i++) xi[i] = x[v * 32 + i];
        float a[16];
#pragma unroll
        for (int j = 0; j < 16; j++) a[j] = nb1[j];
#pragma unroll
        for (int i = 0; i < 32; i++)
#pragma unroll
            for (int j = 0; j < 16; j++) a[j] = fmaf(xi[i], nw1[i * 16 + j], a[j]);
#pragma unroll
        for (int j = 0; j < 16; j++) a[j] = fmaxf(a[j], 0.f);
        float o[16];
#pragma unroll
        for (int j = 0; j < 16; j++) o[j] = nb2[j];
#pragma unroll
        for (int i = 0; i < 16; i++)
#pragma unroll
            for (int j = 0; j < 16; j++) o[j] = fmaf(a[i], nw2[i * 16 + j], o[j]);
#pragma unroll
        for (int j = 0; j < 16; j++) { hf[v * 16 + j] = o[j]; h16o[v * 16 + j] = (f16)o[j]; }
    } else {
        int bb = b - 384;
        int mol = bb >> 8;
        const int* ei = mol ? eip : eir;
        const float* pos = mol ? posp : posr;
        float* sh_ = sh1d + (size_t)mol * NE * 4;
        f16* em_ = eemb16 + (size_t)mol * NE * 16;
        int* cn_ = cnt + mol * NN;
        int e = (bb & 255) * 256 + tid;
        int s = ei[e], d = ei[NE + e];
        float ex = pos[d * 3 + 0] - pos[s * 3 + 0];
        float ey = pos[d * 3 + 1] - pos[s * 3 + 1];
        float ez = pos[d * 3 + 2] - pos[s * 3 + 2];
        float dist = sqrtf(ex * ex + ey * ey + ez * ez + 1e-12f);
        float inv = SQRT3F / dist;
        sh_[e * 4 + 0] = ex * inv;
        sh_[e * 4 + 1] = ey * inv;
        sh_[e * 4 + 2] = ez * inv;
        sh_[e * 4 + 3] = dist;
        float g[32];
#pragma unroll
        for (int i = 0; i < 32; i++) {
            float t = dist - (float)i * GSTEP;
            g[i] = __expf(GCOEFF * t * t);
        }
        float a[16];
#pragma unroll
        for (int j = 0; j < 16; j++) a[j] = eb1[j];
#pragma unroll
        for (int i = 0; i < 32; i++)
#pragma unroll
            for (int j = 0; j < 16; j++) a[j] = fmaf(g[i], ew1[i * 16 + j], a[j]);
#pragma unroll
        for (int j = 0; j < 16; j++) a[j] = fmaxf(a[j], 0.f);
        float o[16];
#pragma unroll
        for (int j = 0; j < 16; j++) o[j] = eb2[j];
#pragma unroll
        for (int i = 0; i < 16; i++)
#pragma unroll
            for (int j = 0; j < 16; j++) o[j] = fmaf(a[i], ew2[i * 16 + j], o[j]);
#pragma unroll
        for (int j = 0; j < 16; j++) em_[e * 16 + j] = (f16)o[j];
        atomicAdd(&cn_[d], 1);
    }
}

// ============ fused scan+fill: each block redundantly scans cnt in LDS, then fills its 256 edges ============
__global__ __launch_bounds__(256) void k_fillscan(const int* __restrict__ eir, const int* __restrict__ eip,
                                                  const int* __restrict__ cnt, int* __restrict__ fillc,
                                                  int* __restrict__ rowptr, int* __restrict__ eord,
                                                  float* __restrict__ out) {
    __shared__ int rpl[NN];
    __shared__ int part[256];
    int mol = blockIdx.y;
    int cb = blockIdx.x;
    int tid = threadIdx.x;
    const int* c = cnt + mol * NN;
    int base = tid * (NN / 256);
    int s = 0;
#pragma unroll
    for (int i = 0; i < NN / 256; i++) s += c[base + i];
    part[tid] = s;
    __syncthreads();
    if (tid == 0) {
        int run = 0;
        for (int i = 0; i < 256; i++) { int v = part[i]; part[i] = run; run += v; }
    }
    __syncthreads();
    {
        int run = part[tid];
        for (int i = 0; i < NN / 256; i++) {
            rpl[base + i] = run;
            run += c[base + i];
        }
        if (cb == 0) {       // block 0 publishes global rowptr for the gather kernels
            int r2 = part[tid];
            int* rp = rowptr + mol * (NN + 1);
            for (int i = 0; i < NN / 256; i++) {
                rp[base + i] = r2;
                r2 += c[base + i];
            }
            if (tid == 255) rp[NN] = r2;
            if (mol == 0 && tid < 64) out[tid] = 0.f;
        }
    }
    __syncthreads();
    const int* ei = mol ? eip : eir;
    int e = cb * 256 + tid;
    int d = ei[NE + e];
    int pos = atomicAdd(&fillc[mol * NN + d], 1);
    eord[mol * NE + rpl[d] + pos] = e;
}

// ============ conv0: 256 edges/block (2 waves x 128), eord-ordered, f16 tp0[i][4][16] ============
__global__ __launch_bounds__(128) void k_conv0(const int* __restrict__ eir, const int* __restrict__ eip,
                                               const int* __restrict__ eord,
                                               const f16* __restrict__ eemb16, const f16* __restrict__ h16_16,
                                               const float* __restrict__ sh1d,
                                               const f16* __restrict__ w1h, const f16* __restrict__ w2h,
                                               f16* __restrict__ tp0) {
    __shared__ __align__(16) f16 ea[256 * 72];     // 144B/row, reused as hid (36 KB)
    __shared__ __align__(16) f16 sc0[256 * 24];    // 48B/row: 16 xu f16 (12 KB)
    __shared__ __align__(16) float4 shs[256];      // 4 KB
    int mol = blockIdx.y;
    const int* ei = mol ? eip : eir;
    const int* eo = eord + mol * NE;
    const f16* em_ = eemb16 + (size_t)mol * NE * 16;
    const f16* h16_ = h16_16 + (size_t)mol * NN * 16;
    const float* sh_ = sh1d + (size_t)mol * NE * 4;
    f16* tp_ = tp0 + (size_t)mol * NE * 64;
    int tid = threadIdx.x;
    int e0 = blockIdx.x * 256;
#pragma unroll
    for (int ii = 0; ii < 2; ii++) {
        int er = tid * 2 + ii;
        int le = eo[e0 + er];
        int s = ei[le], d = ei[NE + le];
        char* row = (char*)ea + er * 144;
        const f16x8* pe = (const f16x8*)(em_ + (size_t)le * 16);
        ((f16x8*)row)[0] = pe[0]; ((f16x8*)row)[1] = pe[1];
        const f16x8* pd = (const f16x8*)(h16_ + (size_t)d * 16);
        ((f16x8*)row)[2] = pd[0]; ((f16x8*)row)[3] = pd[1];
        const f16x8* ps = (const f16x8*)(h16_ + (size_t)s * 16);
        f16x8 sv0 = ps[0], sv1 = ps[1];
        ((f16x8*)row)[4] = sv0; ((f16x8*)row)[5] = sv1;
        f16x8 z = {}; f16x8 o = {}; o[0] = (f16)1.0f;
        ((f16x8*)row)[6] = o; ((f16x8*)row)[7] = z; ((f16x8*)row)[8] = z;
        char* srow = (char*)sc0 + er * 48;
        *(f16x8*)srow = sv0;
        *(f16x8*)(srow + 16) = sv1;
        shs[er] = *(const float4*)(sh_ + (size_t)le * 4);
    }
    int wv = tid >> 6, l = tid & 63;
    int koff = (l >> 4) * 16;
    int voffB = (l & 15) * 128 + koff;
    int rbase = wv * 128;
#pragma unroll
    for (int t = 0; t < 8; t++) {
        int arow = rbase + t * 16 + (l & 15);
        f16x8 a0 = *(const f16x8*)((const char*)ea + arow * 144 + koff);
        f16x8 a1 = *(const f16x8*)((const char*)ea + arow * 144 + koff + 64);
#pragma unroll
        for (int nt = 0; nt < 3; nt++) {
            f32x4 hacc = {0.f, 0.f, 0.f, 0.f};
            const char* hb = (const char*)w1h + nt * 2048 + voffB;
            MFMA(hacc, a0, *(const f16x8*)(hb));
            MFMA(hacc, a1, *(const f16x8*)(hb + 64));
#pragma unroll
            for (int r = 0; r < 4; r++) {
                int rr = rbase + t * 16 + (l >> 4) * 4 + r;
                ea[rr * 72 + nt * 16 + (l & 15)] = (f16)fmaxf(hacc[r], 0.f);
            }
        }
    }
    f16x8 ha0[8], ha1[8];
#pragma unroll
    for (int t = 0; t < 8; t++) {
        int arow = rbase + t * 16 + (l & 15);
        ha0[t] = *(const f16x8*)((const char*)ea + arow * 144 + koff);
        ha1[t] = *(const f16x8*)((const char*)ea + arow * 144 + koff + 64);
    }
    f32x4 accA[8] = {}, accB[8] = {};
    const char* wB = (const char*)w2h + voffB;
    f16x8 cA0 = *(const f16x8*)(wB), cA1 = *(const f16x8*)(wB + 64);
    f16x8 cB0 = *(const f16x8*)(wB + 32768), cB1 = *(const f16x8*)(wB + 32768 + 64);
#pragma unroll 4
    for (int u = 0; u < 16; ++u) {
        int un = (u < 15) ? u + 1 : 15;
        const char* Hb = wB + un * 2048;
        f16x8 nA0 = *(const f16x8*)(Hb), nA1 = *(const f16x8*)(Hb + 64);
        f16x8 nB0 = *(const f16x8*)(Hb + 32768), nB1 = *(const f16x8*)(Hb + 32768 + 64);
#pragma unroll
        for (int t = 0; t < 8; t++) {
            f16 s = *(const f16*)((const char*)sc0 + (rbase + t * 16 + (l & 15)) * 48 + u * 2);
            f16x8 x0 = ha0[t] * s, x1 = ha1[t] * s;
            MFMA(accA[t], x0, cA0); MFMA(accA[t], x1, cA1);
            MFMA(accB[t], x0, cB0); MFMA(accB[t], x1, cB1);
        }
        cA0 = nA0; cA1 = nA1; cB0 = nB0; cB1 = nB1;
    }
    int w = l & 15;
#pragma unroll
    for (int t = 0; t < 8; t++)
#pragma unroll
        for (int r = 0; r < 4; r++) {
            int ro = rbase + t * 16 + (l >> 4) * 4 + r;
            int i = e0 + ro;
            float4 shv = shs[ro];
            f16* tpp = tp_ + (size_t)i * 64;
            float tb = 0.25f * accB[t][r];
            tpp[w] = (f16)(0.25f * accA[t][r]);
            tpp[16 + w] = (f16)(tb * shv.x);
            tpp[32 + w] = (f16)(tb * shv.y);
            tpp[48 + w] = (f16)(tb * shv.z);
        }
}

// ---------------- gather conv0 (sequential, f16 tp) -> FULL f16 h64[64ch] + f32 h0f[16ch] ----------------
__global__ __launch_bounds__(256) void k_up0g(const float* __restrict__ h16f, const f16* __restrict__ tp0,
                                              const int* __restrict__ rowptr,
                                              f16* __restrict__ h64_16, float* __restrict__ h0f) {
    int mol = blockIdx.y;
    const float* h_ = h16f + (size_t)mol * NN * 16;
    const f16* tp = tp0 + (size_t)mol * NE * 64;
    const int* rp = rowptr + mol * (NN + 1);
    f16* o16_ = h64_16 + (size_t)mol * NN * 64;
    float* o0_ = h0f + (size_t)mol * NN * 16;
    int tid = threadIdx.x;
    int v = blockIdx.x * 64 + (tid >> 2), q = tid & 3;
    int r0 = rp[v], r1 = rp[v + 1];
    float acc[16];
#pragma unroll
    for (int j = 0; j < 16; j++) acc[j] = 0.f;
    for (int i = r0; i < r1; i++) {
        const f16* src = tp + (size_t)i * 64 + q * 16;
        f16x8 v0 = *(const f16x8*)src;
        f16x8 v1 = *(const f16x8*)(src + 8);
#pragma unroll
        for (int j = 0; j < 8; j++) { acc[j] += (float)v0[j]; acc[8 + j] += (float)v1[j]; }
    }
    float rc = 1.0f / fmaxf((float)(r1 - r0), 1.0f);
    if (q == 0) {
#pragma unroll
        for (int w = 0; w < 16; w++) {
            float val = fmaf(acc[w], rc, h_[(size_t)v * 16 + w]);
            o0_[(size_t)v * 16 + w] = val;
            o16_[(size_t)v * 64 + w] = (f16)val;
        }
    } else {
#pragma unroll
        for (int w = 0; w < 16; w++) o16_[(size_t)v * 64 + 16 + 3 * w + (q - 1)] = (f16)(acc[w] * rc);
    }
}

// ============ conv1: mats A+D; 256 edges/block; staging fully from f16 h64; f16 tp1 ============
__global__ __launch_bounds__(128) void k_conv1(const int* __restrict__ eir, const int* __restrict__ eip,
                                               const int* __restrict__ eord,
                                               const f16* __restrict__ eemb16, const f16* __restrict__ h64_16,
                                               const float* __restrict__ sh1d,
                                               const f16* __restrict__ w1h, const f16* __restrict__ w2h,
                                               f16* __restrict__ tp1) {
    __shared__ __align__(16) f16 ea[256 * 72];     // 36 KB
    __shared__ __align__(16) f16 sc1[256 * 36];    // 72B/row: 16u x f16x2{xu,du} (18 KB)
    int mol = blockIdx.y;
    const int* ei = mol ? eip : eir;
    const int* eo = eord + mol * NE;
    const f16* em_ = eemb16 + (size_t)mol * NE * 16;
    const f16* h64_ = h64_16 + (size_t)mol * NN * 64;
    const float* sh_ = sh1d + (size_t)mol * NE * 4;
    f16* tp_ = tp1 + (size_t)mol * NE * 16;
    int tid = threadIdx.x;
    int e0 = blockIdx.x * 256;
#pragma unroll
    for (int ii = 0; ii < 2; ii++) {
        int er = tid * 2 + ii;
        int le = eo[e0 + er];
        int s = ei[le], d = ei[NE + le];
        char* row = (char*)ea + er * 144;
        const f16x8* pe = (const f16x8*)(em_ + (size_t)le * 16);
        ((f16x8*)row)[0] = pe[0]; ((f16x8*)row)[1] = pe[1];
        const f16x8* pd = (const f16x8*)(h64_ + (size_t)d * 64);
        ((f16x8*)row)[2] = pd[0]; ((f16x8*)row)[3] = pd[1];
        const f16* hs = h64_ + (size_t)s * 64;
        const f16x8* ps = (const f16x8*)hs;
        f16x8 hs0 = ps[0], hs1 = ps[1];
        ((f16x8*)row)[4] = hs0; ((f16x8*)row)[5] = hs1;
        f16x8 z = {}; f16x8 o = {}; o[0] = (f16)1.0f;
        ((f16x8*)row)[6] = o; ((f16x8*)row)[7] = z; ((f16x8*)row)[8] = z;
        float4 shv = *(const float4*)(sh_ + (size_t)le * 4);
        float xu[16];
#pragma unroll
        for (int j = 0; j < 8; j++) { xu[j] = (float)hs0[j]; xu[8 + j] = (float)hs1[j]; }
        float x1v[48];
#pragma unroll
        for (int g = 0; g < 6; g++) {
            f16x8 v8 = ps[2 + g];
#pragma unroll
            for (int j = 0; j < 8; j++) x1v[g * 8 + j] = (float)v8[j];
        }
        char* srow = (char*)sc1 + er * 72;
#pragma unroll
        for (int g = 0; g < 4; g++) {
            f16x8 pk;
#pragma unroll
            for (int k2 = 0; k2 < 4; k2++) {
                int k = g * 4 + k2;
                float du = (x1v[k * 3] * shv.x + x1v[k * 3 + 1] * shv.y + x1v[k * 3 + 2] * shv.z) * INV_SQRT3F;
                pk[k2 * 2 + 0] = (f16)xu[k];
                pk[k2 * 2 + 1] = (f16)du;
            }
            *(f16x8*)(srow + g * 16) = pk;
        }
    }
    int wv = tid >> 6, l = tid & 63;
    int koff = (l >> 4) * 16;
    int voffB = (l & 15) * 128 + koff;
    int rbase = wv * 128;
#pragma unroll
    for (int t = 0; t < 8; t++) {
        int arow = rbase + t * 16 + (l & 15);
        f16x8 a0 = *(const f16x8*)((const char*)ea + arow * 144 + koff);
        f16x8 a1 = *(const f16x8*)((const char*)ea + arow * 144 + koff + 64);
#pragma unroll
        for (int nt = 0; nt < 3; nt++) {
            f32x4 hacc = {0.f, 0.f, 0.f, 0.f};
            const char* hb = (const char*)w1h + nt * 2048 + voffB;
            MFMA(hacc, a0, *(const f16x8*)(hb));
            MFMA(hacc, a1, *(const f16x8*)(hb + 64));
#pragma unroll
            for (int r = 0; r < 4; r++) {
                int rr = rbase + t * 16 + (l >> 4) * 4 + r;
                ea[rr * 72 + nt * 16 + (l & 15)] = (f16)fmaxf(hacc[r], 0.f);
            }
        }
    }
    f16x8 ha0[8], ha1[8];
#pragma unroll
    for (int t = 0; t < 8; t++) {
        int arow = rbase + t * 16 + (l & 15);
        ha0[t] = *(const f16x8*)((const char*)ea + arow * 144 + koff);
        ha1[t] = *(const f16x8*)((const char*)ea + arow * 144 + koff + 64);
    }
    f32x4 accA[8] = {};
    const char* wB = (const char*)w2h + voffB;
    f16x8 cA0 = *(const f16x8*)(wB), cA1 = *(const f16x8*)(wB + 64);
    f16x8 cD0 = *(const f16x8*)(wB + 98304), cD1 = *(const f16x8*)(wB + 98304 + 64);
#pragma unroll 4
    for (int u = 0; u < 16; ++u) {
        int un = (u < 15) ? u + 1 : 15;
        const char* Hb = wB + un * 2048;
        f16x8 nA0 = *(const f16x8*)(Hb), nA1 = *(const f16x8*)(Hb + 64);
        f16x8 nD0 = *(const f16x8*)(Hb + 98304), nD1 = *(const f16x8*)(Hb + 98304 + 64);
#pragma unroll
        for (int t = 0; t < 8; t++) {
            f16x2 sp = *(const f16x2*)((const char*)sc1 + (rbase + t * 16 + (l & 15)) * 72 + u * 4);
            f16x8 x0 = ha0[t] * sp[0], x1 = ha1[t] * sp[0];
            MFMA(accA[t], x0, cA0); MFMA(accA[t], x1, cA1);
            x0 = ha0[t] * sp[1]; x1 = ha1[t] * sp[1];
            MFMA(accA[t], x0, cD0); MFMA(accA[t], x1, cD1);
        }
        cA0 = nA0; cA1 = nA1; cD0 = nD0; cD1 = nD1;
    }
    int w = l & 15;
#pragma unroll
    for (int t = 0; t < 8; t++)
#pragma unroll
        for (int r = 0; r < 4; r++) {
            int i = e0 + rbase + t * 16 + (l >> 4) * 4 + r;
            tp_[(size_t)i * 16 + w] = (f16)(PW * accA[t][r]);
        }
}

// ---------------- gather conv1 (sequential, f16 tp) -> xf16; s_nodes MLP; bucket into out ----------------
__global__ __launch_bounds__(256) void k_xfg(const float* __restrict__ h0f, const f16* __restrict__ tp1,
                                             const int* __restrict__ rowptr,
                                             f16* __restrict__ xf16,
                                             const int* __restrict__ batchr, const int* __restrict__ batchp,
                                             const float* __restrict__ w1, const float* __restrict__ b1,
                                             const float* __restrict__ w2, const float* __restrict__ b2,
                                             const float* __restrict__ w3, const float* __restrict__ b3,
                                             float* __restrict__ out) {
    __shared__ float xfs[64][17];
    __shared__ float buck[64];
    int tid = threadIdx.x;
    if (tid < 64) buck[tid] = 0.f;
    int mol = blockIdx.y;
    float sign = mol ? 1.f : -1.f;
    const int* batch = mol ? batchp : batchr;
    const float* h_ = h0f + (size_t)mol * NN * 16;
    const f16* tp = tp1 + (size_t)mol * NE * 16;
    const int* rp = rowptr + mol * (NN + 1);
    f16* xf_ = xf16 + (size_t)mol * NN * 16;
    int v = blockIdx.x * 64 + (tid >> 2), q = tid & 3;
    int r0 = rp[v], r1 = rp[v + 1];
    float a0 = 0.f, a1 = 0.f, a2 = 0.f, a3 = 0.f;
    for (int i = r0; i < r1; i++) {
        f16x4 t4 = *(const f16x4*)(tp + (size_t)i * 16 + q * 4);
        a0 += (float)t4[0]; a1 += (float)t4[1]; a2 += (float)t4[2]; a3 += (float)t4[3];
    }
    float rc = 1.0f / fmaxf((float)(r1 - r0), 1.0f);
    float4 hv = *(const float4*)(h_ + (size_t)v * 16 + q * 4);
    float x0 = fmaf(a0, rc, hv.x), x1 = fmaf(a1, rc, hv.y);
    float x2 = fmaf(a2, rc, hv.z), x3 = fmaf(a3, rc, hv.w);
    xfs[tid >> 2][q * 4 + 0] = x0; xfs[tid >> 2][q * 4 + 1] = x1;
    xfs[tid >> 2][q * 4 + 2] = x2; xfs[tid >> 2][q * 4 + 3] = x3;
    f16x4 xo = {(f16)x0, (f16)x1, (f16)x2, (f16)x3};
    *(f16x4*)(xf_ + (size_t)v * 16 + q * 4) = xo;
    __syncthreads();
    if (tid < 64) {
        int v2 = blockIdx.x * 64 + tid;
        float xv[16];
#pragma unroll
        for (int c = 0; c < 16; c++) xv[c] = xfs[tid][c];
        float aa[32];
#pragma unroll
        for (int j = 0; j < 32; j++) aa[j] = b1[j];
#pragma unroll
        for (int i = 0; i < 16; i++)
#pragma unroll
            for (int j = 0; j < 32; j++) aa[j] = fmaf(xv[i], w1[i * 32 + j], aa[j]);
#pragma unroll
        for (int j = 0; j < 32; j++) aa[j] = fmaxf(aa[j], 0.f);
        float bb[16];
#pragma unroll
        for (int j = 0; j < 16; j++) bb[j] = b2[j];
#pragma unroll
        for (int i = 0; i < 32; i++)
#pragma unroll
            for (int j = 0; j < 16; j++) bb[j] = fmaf(aa[i], w2[i * 16 + j], bb[j]);
#pragma unroll
        for (int j = 0; j < 16; j++) bb[j] = fmaxf(bb[j], 0.f);
        float val = b3[0];
#pragma unroll
        for (int i = 0; i < 16; i++) val = fmaf(bb[i], w3[i], val);
        atomicAdd(&buck[batch[v2]], val);
    }
    __syncthreads();
    if (tid < 64) atomicAdd(&out[tid], sign * buck[tid]);
}

// ---------------- s_edges MLP (64->16->16->1), xf gathered as f16, bucket by batch[src] ----------------
__global__ __launch_bounds__(256) void k_sedge(const int* __restrict__ eir, const int* __restrict__ eip,
                                               const int* __restrict__ batchr, const int* __restrict__ batchp,
                                               const float* __restrict__ sh1d, const f16* __restrict__ xf16,
                                               const float* __restrict__ w1, const float* __restrict__ b1,
                                               const float* __restrict__ w2, const float* __restrict__ b2,
                                               const float* __restrict__ w3, const float* __restrict__ b3,
                                               float* __restrict__ out) {
    __shared__ float buck[64];
    int tid = threadIdx.x;
    if (tid < 64) buck[tid] = 0.f;
    __syncthreads();
    int mol = blockIdx.y;
    float sign = mol ? 1.f : -1.f;
    const int* ei = mol ? eip : eir;
    const int* batch = mol ? batchp : batchr;
    const float* sh_ = sh1d + (size_t)mol * NE * 4;
    const f16* xf_ = xf16 + (size_t)mol * NN * 16;
    int e = blockIdx.x * 256 + tid;
    int s = ei[e], d = ei[NE + e];
    float dist = sh_[e * 4 + 3];
    float in[64];
#pragma unroll
    for (int i = 0; i < 32; i++) {
        float t = dist - (float)i * GSTEP;
        in[i] = __expf(GCOEFF * t * t);
    }
    {
        f16x8 s0v = *(const f16x8*)(xf_ + (size_t)s * 16);
        f16x8 s1v = *(const f16x8*)(xf_ + (size_t)s * 16 + 8);
        f16x8 d0v = *(const f16x8*)(xf_ + (size_t)d * 16);
        f16x8 d1v = *(const f16x8*)(xf_ + (size_t)d * 16 + 8);
#pragma unroll
        for (int i = 0; i < 8; i++) {
            in[32 + i] = (float)s0v[i]; in[40 + i] = (float)s1v[i];
            in[48 + i] = (float)d0v[i]; in[56 + i] = (float)d1v[i];
        }
    }
    float a[16];
#pragma unroll
    for (int j = 0; j < 16; j++) a[j] = b1[j];
#pragma unroll
    for (int i = 0; i < 64; i++)
#pragma unroll
        for (int j = 0; j < 16; j++) a[j] = fmaf(in[i], w1[i * 16 + j], a[j]);
#pragma unroll
    for (int j = 0; j < 16; j++) a[j] = fmaxf(a[j], 0.f);
    float bb[16];
#pragma unroll
    for (int j = 0; j < 16; j++) bb[j] = b2[j];
#pragma unroll
    for (int i = 0; i < 16; i++)
#pragma unroll
        for (int j = 0; j < 16; j++) bb[j] = fmaf(a[i], w2[i * 16 + j], bb[j]);
#pragma unroll
    for (int j = 0; j < 16; j++) bb[j] = fmaxf(bb[j], 0.f);
    float val = b3[0];
#pragma unroll
    for (int i = 0; i < 16; i++) val = fmaf(bb[i], w3[i], val);
    atomicAdd(&buck[batch[s]], val);
    __syncthreads();
    if (tid < 64) atomicAdd(&out[tid], sign * buck[tid]);
}

extern "C" void kernel_launch(void* const* d_in, const int* in_sizes, int n_in,
                              void* d_out, int out_size, void* d_ws, size_t ws_size,
                              hipStream_t stream) {
    const float* x_r = (const float*)d_in[0];
    const float* pos_r = (const float*)d_in[1];
    const int* ei_r = (const int*)d_in[2];
    const int* batch_r = (const int*)d_in[3];
    const float* x_p = (const float*)d_in[4];
    const float* pos_p = (const float*)d_in[5];
    const int* ei_p = (const int*)d_in[6];
    const int* batch_p = (const int*)d_in[7];
    const float* ne_w1 = (const float*)d_in[8];
    const float* ne_b1 = (const float*)d_in[9];
    const float* ne_w2 = (const float*)d_in[10];
    const float* ne_b2 = (const float*)d_in[11];
    const float* ee_w1 = (const float*)d_in[12];
    const float* ee_b1 = (const float*)d_in[13];
    const float* ee_w2 = (const float*)d_in[14];
    const float* ee_b2 = (const float*)d_in[15];
    const float* c0_w1 = (const float*)d_in[16];
    const float* c0_b1 = (const float*)d_in[17];
    const float* c0_w2 = (const float*)d_in[18];
    const float* c0_b2 = (const float*)d_in[19];
    const float* c1_w1 = (const float*)d_in[20];
    const float* c1_b1 = (const float*)d_in[21];
    const float* c1_w2 = (const float*)d_in[22];
    const float* c1_b2 = (const float*)d_in[23];
    const float* sn_w1 = (const float*)d_in[24];
    const float* sn_b1 = (const float*)d_in[25];
    const float* sn_w2 = (const float*)d_in[26];
    const float* sn_b2 = (const float*)d_in[27];
    const float* sn_w3 = (const float*)d_in[28];
    const float* sn_b3 = (const float*)d_in[29];
    const float* se_w1 = (const float*)d_in[30];
    const float* se_b1 = (const float*)d_in[31];
    const float* se_w2 = (const float*)d_in[32];
    const float* se_b2 = (const float*)d_in[33];
    const float* se_w3 = (const float*)d_in[34];
    const float* se_b3 = (const float*)d_in[35];
    float* out = (float*)d_out;

    char* p = (char*)d_ws;
    auto alloc = [&](size_t bytes) { char* r = p; p += (bytes + 255) & ~(size_t)255; return r; };
    f16* w2t1 = (f16*)alloc(1280 * 64 * 2);
    f16* w2t0 = (f16*)alloc(512 * 64 * 2);
    f16* w1c0 = (f16*)alloc(48 * 64 * 2);
    f16* w1c1 = (f16*)alloc(48 * 64 * 2);
    f16* eemb16 = (f16*)alloc((size_t)2 * NE * 16 * 2);
    f16* h16_16 = (f16*)alloc((size_t)2 * NN * 16 * 2);
    f16* h64_16 = (f16*)alloc((size_t)2 * NN * 64 * 2);
    float* h16f = (float*)alloc((size_t)2 * NN * 16 * 4);
    float* sh1d = (float*)alloc((size_t)2 * NE * 4 * 4);
    int* cntI = (int*)alloc((size_t)2 * NN * 4);
    int* fillc = (int*)alloc((size_t)2 * NN * 4);      // adjacent to cntI -> one memset
    int* rowptr = (int*)alloc((size_t)2 * (NN + 1) * 4);
    int* eord = (int*)alloc((size_t)2 * NE * 4);
    f16* tp0 = (f16*)alloc((size_t)2 * NE * 64 * 2);
    f16* tp1 = tp0;                                     // reused after k_up0g consumes tp0
    float* h0f = (float*)alloc((size_t)2 * NN * 16 * 4);
    f16* xf16 = (f16*)alloc((size_t)2 * NN * 16 * 2);
    (void)ws_size; (void)n_in; (void)in_sizes; (void)out_size;

    hipMemsetAsync(cntI, 0, (size_t)2 * NN * 4 * 2, stream);   // cnt + fillc

    dim3 blk256(256, 1, 1), blk128(128, 1, 1);
    dim3 ge(NE / 256, 2, 1);
    dim3 gc(NE / 256, 2, 1);

    k_pre<<<dim3(896, 1, 1), blk256, 0, stream>>>(c0_w1, c0_b1, c1_w1, c1_b1, c0_w2, c0_b2, c1_w2, c1_b2,
                                                  w1c0, w1c1, w2t0, w2t1,
                                                  x_r, x_p, h16f, h16_16, ne_w1, ne_b1, ne_w2, ne_b2,
                                                  ei_r, ei_p, pos_r, pos_p, sh1d, eemb16, cntI,
                                                  ee_w1, ee_b1, ee_w2, ee_b2);
    k_fillscan<<<ge, blk256, 0, stream>>>(ei_r, ei_p, cntI, fillc, rowptr, eord, out);
    k_conv0<<<gc, blk128, 0, stream>>>(ei_r, ei_p, eord, eemb16, h16_16, sh1d, w1c0, w2t0, tp0);
    k_up0g<<<dim3(NN / 64, 2, 1), blk256, 0, stream>>>(h16f, tp0, rowptr, h64_16, h0f);
    k_conv1<<<gc, blk128, 0, stream>>>(ei_r, ei_p, eord, eemb16, h64_16, sh1d, w1c1, w2t1, tp1);
    k_xfg<<<dim3(NN / 64, 2, 1), blk256, 0, stream>>>(h0f, tp1, rowptr, xf16, batch_r, batch_p,
                                                      sn_w1, sn_b1, sn_w2, sn_b2, sn_w3, sn_b3, out);
    k_sedge<<<ge, blk256, 0, stream>>>(ei_r, ei_p, batch_r, batch_p, sh1d, xf16,
                                       se_w1, se_b1, se_w2, se_b2, se_w3, se_b3, out);
}